// Round 1
// baseline (361.409 us; speedup 1.0000x reference)
//
#include <hip/hip_runtime.h>
#include <math.h>

#define B_    16
#define P_    25
#define D_SL_ 32
#define H_    320
#define W_    320
#define C_    64
#define BP    400           // B*P
#define KPIX  4096          // C*C
#define FIN   12288         // 3*C*C
#define FOUT  1280
#define HID   128
#define NG    3

// ws layout (float offsets)
#define WS_CROP   0
#define WS_FEATS  (BP * KPIX)              // 1,638,400
#define WS_LOGITS (WS_FEATS + BP * FOUT)   // 2,150,400
// total floats: 2,151,600  (~8.6 MB)

// ---------------- kernel 1: crop gather ----------------
__global__ __launch_bounds__(256) void crops_kernel(
    const float* __restrict__ images,
    const float* __restrict__ z_pred,
    const float* __restrict__ xy_pred,
    float* __restrict__ crop)
{
    int pt = blockIdx.x;            // 0..399
    int b  = pt / P_;
    // jnp.round == round-half-even == rintf
    int z = (int)rintf(z_pred[pt] - 1.0f);
    z = min(max(z, 0), D_SL_ - 1);
    int x = (int)rintf(4.0f * xy_pred[pt * 2 + 0]);   // W*xy/XY_MAX = 4*xy
    int y = (int)rintf(4.0f * xy_pred[pt * 2 + 1]);
    x = min(max(x, 0), W_ - 1);
    y = min(max(y, 0), H_ - 1);
    const float* img = images + (size_t)(b * D_SL_ + z) * (H_ * W_);
    for (int i = threadIdx.x; i < C_ * C_; i += 256) {
        int r = i >> 6, c = i & 63;
        int iy = y - 32 + r;
        int ix = x - 32 + c;
        float v = 0.0f;
        if ((unsigned)iy < (unsigned)H_ && (unsigned)ix < (unsigned)W_)
            v = img[iy * W_ + ix];
        crop[(size_t)pt * KPIX + i] = v;
    }
}

// ---------------- kernel 2: feats = crop @ Wsum + b_feat ----------------
// Wsum[k][n] = W_feat[k][n] + W_feat[k+4096][n] + W_feat[k+8192][n] (on the fly)
#define KC 32
__global__ __launch_bounds__(256) void gemm_kernel(
    const float* __restrict__ crop,
    const float* __restrict__ Wf,
    const float* __restrict__ bf,
    float* __restrict__ feats)
{
    __shared__ float As[KC][C_];      // As[k][m]
    __shared__ float Bs[KC][68];      // Bs[k][n], padded row

    int n0 = blockIdx.x * 64;         // 0..19 tiles
    int m0 = blockIdx.y * 64;         // 0..6 tiles
    int t  = threadIdx.x;

    float acc[4][4];
    #pragma unroll
    for (int i = 0; i < 4; ++i)
        #pragma unroll
        for (int j = 0; j < 4; ++j) acc[i][j] = 0.0f;

    int tm = (t >> 4) << 2;           // 0..60
    int tn = (t & 15) << 2;           // 0..60

    for (int k0 = 0; k0 < KPIX; k0 += KC) {
        // A tile: 64 rows x 32 k  (512 float4, 2 per thread)
        #pragma unroll
        for (int i = 0; i < 2; ++i) {
            int idx = t + i * 256;
            int row = idx >> 3;           // 0..63
            int kq  = (idx & 7) << 2;     // 0..28
            int m = m0 + row;
            float4 v = make_float4(0.f, 0.f, 0.f, 0.f);
            if (m < BP)
                v = *(const float4*)(crop + (size_t)m * KPIX + k0 + kq);
            As[kq + 0][row] = v.x;
            As[kq + 1][row] = v.y;
            As[kq + 2][row] = v.z;
            As[kq + 3][row] = v.w;
        }
        // B tile: 32 k x 64 n, summing the 3 channel blocks (512 float4-triples)
        #pragma unroll
        for (int i = 0; i < 2; ++i) {
            int idx = t + i * 256;
            int row = idx >> 4;           // 0..31
            int nq  = (idx & 15) << 2;    // 0..60
            const float* base = Wf + (size_t)(k0 + row) * FOUT + n0 + nq;
            float4 a  = *(const float4*)(base);
            float4 b4 = *(const float4*)(base + (size_t)KPIX * FOUT);
            float4 c4 = *(const float4*)(base + (size_t)2 * KPIX * FOUT);
            *(float4*)&Bs[row][nq] = make_float4(a.x + b4.x + c4.x,
                                                 a.y + b4.y + c4.y,
                                                 a.z + b4.z + c4.z,
                                                 a.w + b4.w + c4.w);
        }
        __syncthreads();
        #pragma unroll 8
        for (int k = 0; k < KC; ++k) {
            float4 av = *(const float4*)&As[k][tm];
            float4 bv = *(const float4*)&Bs[k][tn];
            acc[0][0] = fmaf(av.x, bv.x, acc[0][0]);
            acc[0][1] = fmaf(av.x, bv.y, acc[0][1]);
            acc[0][2] = fmaf(av.x, bv.z, acc[0][2]);
            acc[0][3] = fmaf(av.x, bv.w, acc[0][3]);
            acc[1][0] = fmaf(av.y, bv.x, acc[1][0]);
            acc[1][1] = fmaf(av.y, bv.y, acc[1][1]);
            acc[1][2] = fmaf(av.y, bv.z, acc[1][2]);
            acc[1][3] = fmaf(av.y, bv.w, acc[1][3]);
            acc[2][0] = fmaf(av.z, bv.x, acc[2][0]);
            acc[2][1] = fmaf(av.z, bv.y, acc[2][1]);
            acc[2][2] = fmaf(av.z, bv.z, acc[2][2]);
            acc[2][3] = fmaf(av.z, bv.w, acc[2][3]);
            acc[3][0] = fmaf(av.w, bv.x, acc[3][0]);
            acc[3][1] = fmaf(av.w, bv.y, acc[3][1]);
            acc[3][2] = fmaf(av.w, bv.z, acc[3][2]);
            acc[3][3] = fmaf(av.w, bv.w, acc[3][3]);
        }
        __syncthreads();
    }
    // epilogue: + b_feat, store
    #pragma unroll
    for (int i = 0; i < 4; ++i) {
        int m = m0 + tm + i;
        if (m >= BP) break;
        int n = n0 + tn;
        float4 bb = *(const float4*)(bf + n);
        float4 o = make_float4(acc[i][0] + bb.x, acc[i][1] + bb.y,
                               acc[i][2] + bb.z, acc[i][3] + bb.w);
        *(float4*)(feats + (size_t)m * FOUT + n) = o;
    }
}

// ---------------- kernel 3: MLP + softmax ----------------
__global__ __launch_bounds__(256) void mlp_kernel(
    const float* __restrict__ feats,
    const float* __restrict__ W1, const float* __restrict__ b1,
    const float* __restrict__ W2, const float* __restrict__ b2,
    float* __restrict__ probs_out,      // d_out + 1
    float* __restrict__ logits_ws)
{
    __shared__ float sf[8][FOUT];
    __shared__ float sh[8][HID];
    int r0 = blockIdx.x * 8;            // 50 blocks
    int t  = threadIdx.x;

    for (int i = t; i < 8 * FOUT; i += 256) {
        int r = i >> 10;                // i / 1280? no — do it properly
        r = i / FOUT;
        int c = i - r * FOUT;
        sf[r][c] = feats[(size_t)(r0 + r) * FOUT + c];
    }
    __syncthreads();

    int r  = t >> 5;                    // 0..7
    int j0 = t & 31;
    float a0 = b1[j0], a1 = b1[j0 + 32], a2 = b1[j0 + 64], a3 = b1[j0 + 96];
    #pragma unroll 4
    for (int k = 0; k < FOUT; ++k) {
        float a = sf[r][k];
        const float* w = W1 + (size_t)k * HID + j0;
        a0 = fmaf(a, w[0],  a0);
        a1 = fmaf(a, w[32], a1);
        a2 = fmaf(a, w[64], a2);
        a3 = fmaf(a, w[96], a3);
    }
    sh[r][j0]      = fmaxf(a0, 0.0f);
    sh[r][j0 + 32] = fmaxf(a1, 0.0f);
    sh[r][j0 + 64] = fmaxf(a2, 0.0f);
    sh[r][j0 + 96] = fmaxf(a3, 0.0f);
    __syncthreads();

    if (t < 8) {
        float l[NG];
        #pragma unroll
        for (int c = 0; c < NG; ++c) {
            float acc = b2[c];
            for (int j = 0; j < HID; ++j)
                acc = fmaf(sh[t][j], W2[j * NG + c], acc);
            l[c] = acc;
        }
        int row = r0 + t;
        logits_ws[row * NG + 0] = l[0];
        logits_ws[row * NG + 1] = l[1];
        logits_ws[row * NG + 2] = l[2];
        float m = fmaxf(l[0], fmaxf(l[1], l[2]));
        float e0 = expf(l[0] - m), e1 = expf(l[1] - m), e2 = expf(l[2] - m);
        float inv = 1.0f / (e0 + e1 + e2);
        probs_out[row * NG + 0] = e0 * inv;
        probs_out[row * NG + 1] = e1 * inv;
        probs_out[row * NG + 2] = e2 * inv;
    }
}

// ---------------- kernel 4: grade loss ----------------
__global__ __launch_bounds__(512) void loss_kernel(
    const float* __restrict__ logits,
    const int* __restrict__ grade,
    float* __restrict__ out0)
{
    __shared__ float snum[512];
    __shared__ float sden[512];
    int t = threadIdx.x;
    float num = 0.0f, den = 0.0f;
    for (int p = t; p < BP; p += 512) {
        int g = grade[p];
        float l = logits[p * NG + g];
        l = fminf(fmaxf(l, 1e-5f), 1.0f - 1e-5f);
        float wt = (g == 0) ? 1.0f : (g == 1 ? 2.0f : 4.0f);
        num += wt * logf(l);
        den += wt;
    }
    snum[t] = num; sden[t] = den;
    __syncthreads();
    for (int s = 256; s > 0; s >>= 1) {
        if (t < s) { snum[t] += snum[t + s]; sden[t] += sden[t + s]; }
        __syncthreads();
    }
    if (t == 0) out0[0] = -snum[0] / sden[0];
}

// ---------------- launch ----------------
extern "C" void kernel_launch(void* const* d_in, const int* in_sizes, int n_in,
                              void* d_out, int out_size, void* d_ws, size_t ws_size,
                              hipStream_t stream) {
    const float* images  = (const float*)d_in[0];
    const float* z_pred  = (const float*)d_in[1];
    const float* xy_pred = (const float*)d_in[2];
    const int*   grade   = (const int*)d_in[3];
    const float* W_feat  = (const float*)d_in[4];
    const float* b_feat  = (const float*)d_in[5];
    const float* W1      = (const float*)d_in[6];
    const float* b1      = (const float*)d_in[7];
    const float* W2      = (const float*)d_in[8];
    const float* b2      = (const float*)d_in[9];

    float* out = (float*)d_out;
    float* ws  = (float*)d_ws;
    float* crop   = ws + WS_CROP;
    float* feats  = ws + WS_FEATS;
    float* logits = ws + WS_LOGITS;

    crops_kernel<<<BP, 256, 0, stream>>>(images, z_pred, xy_pred, crop);
    gemm_kernel<<<dim3(FOUT / 64, (BP + 63) / 64), 256, 0, stream>>>(crop, W_feat, b_feat, feats);
    mlp_kernel<<<BP / 8, 256, 0, stream>>>(feats, W1, b1, W2, b2, out + 1, logits);
    loss_kernel<<<1, 512, 0, stream>>>(logits, grade, out);
}

// Round 2
// 119.594 us; speedup vs baseline: 3.0220x; 3.0220x over previous
//
#include <hip/hip_runtime.h>
#include <hip/hip_bf16.h>
#include <math.h>

#define B_    16
#define P_    25
#define D_SL_ 32
#define H_    320
#define W_    320
#define C_    64
#define BP    400
#define KPIX  4096
#define FOUT  1280
#define HID   128
#define NG    3

// ---------- new-path geometry ----------
#define M_PAD  448          // 7 tiles of 64
#define NSTEPS 128          // 4096 / 32 k-steps
#define KSPL   4            // K-split
#define CH_STEPS 32         // steps per K-chunk (1024/32)
#define LDSPAD 40           // row stride in LDS/frag reads (pad 32->40 elems)

typedef __attribute__((ext_vector_type(8))) short   bf16x8;
typedef __attribute__((ext_vector_type(8))) ushort  u16x8;
typedef __attribute__((ext_vector_type(4))) float   f32x4;
typedef __attribute__((ext_vector_type(4))) unsigned int u32x4;

// ws byte offsets (new path)
#define OFF_APH  0u
#define OFF_APL  3670016u
#define OFF_WPH  7340032u
#define OFF_WPL  17825792u
#define OFF_PART 28311552u
#define OFF_LOG  36503552u
#define WS_NEED  36508352u

__device__ inline void split_bf16(float x, ushort& hi, ushort& lo) {
    __hip_bfloat16 h = __float2bfloat16(x);
    float hf = __bfloat162float(h);
    __hip_bfloat16 l = __float2bfloat16(x - hf);
    hi = *(ushort*)&h;
    lo = *(ushort*)&l;
}

// ---------------- crops -> paneled bf16 hi/lo  [step][M_PAD][32] ----------------
__global__ __launch_bounds__(128) void crops_split(
    const float* __restrict__ images,
    const float* __restrict__ z_pred,
    const float* __restrict__ xy_pred,
    ushort* __restrict__ APH, ushort* __restrict__ APL)
{
    int pt = blockIdx.x;
    int b  = pt / P_;
    int z = (int)rintf(z_pred[pt] - 1.0f);
    z = min(max(z, 0), D_SL_ - 1);
    int x = (int)rintf(4.0f * xy_pred[pt * 2 + 0]);
    int y = (int)rintf(4.0f * xy_pred[pt * 2 + 1]);
    x = min(max(x, 0), W_ - 1);
    y = min(max(y, 0), H_ - 1);
    const float* img = images + (size_t)(b * D_SL_ + z) * (H_ * W_);

    int t = threadIdx.x;             // 0..127 = k-step index
    int r = t >> 1;                  // crop row 0..63
    int cb = (t & 1) * 32;           // crop col base
    int iy = y - 32 + r;
    bool vy = (iy >= 0) && (iy < H_);
    int iyc = min(max(iy, 0), H_ - 1);
    const float* row = img + (size_t)iyc * W_;

    ushort hi[32], lo[32];
    #pragma unroll
    for (int j = 0; j < 32; ++j) {
        int ix = x - 32 + cb + j;
        float v = 0.0f;
        if (vy && ix >= 0 && ix < W_) v = row[ix];
        split_bf16(v, hi[j], lo[j]);
    }
    ushort* oh = APH + ((size_t)t * M_PAD + pt) * 32;
    ushort* ol = APL + ((size_t)t * M_PAD + pt) * 32;
    #pragma unroll
    for (int q = 0; q < 4; ++q) {
        u16x8 vh, vl;
        #pragma unroll
        for (int e = 0; e < 8; ++e) { vh[e] = hi[q * 8 + e]; vl[e] = lo[q * 8 + e]; }
        *(u16x8*)(oh + q * 8) = vh;
        *(u16x8*)(ol + q * 8) = vl;
    }
}

// ---------------- Wsum = ch0+ch1+ch2 -> paneled bf16 hi/lo [step][1280][32] ----------------
__global__ __launch_bounds__(256) void prep_w(
    const float* __restrict__ Wf,
    ushort* __restrict__ WPH, ushort* __restrict__ WPL)
{
    __shared__ float S[128][68];
    int t = threadIdx.x;
    int k0 = blockIdx.x * 128;       // 32 blocks
    int n0 = blockIdx.y * 64;        // 20 blocks
    #pragma unroll
    for (int p = 0; p < 8; ++p) {
        int kl = p * 16 + (t >> 4);
        int nq = (t & 15) * 4;
        const float* base = Wf + (size_t)(k0 + kl) * FOUT + n0 + nq;
        float4 a = *(const float4*)base;
        float4 b = *(const float4*)(base + (size_t)KPIX * FOUT);
        float4 c = *(const float4*)(base + (size_t)2 * KPIX * FOUT);
        *(float4*)&S[kl][nq] = make_float4(a.x + b.x + c.x, a.y + b.y + c.y,
                                           a.z + b.z + c.z, a.w + b.w + c.w);
    }
    __syncthreads();
    int stepl = t >> 6;              // 0..3
    int nl = t & 63;
    int gstep = blockIdx.x * 4 + stepl;
    ushort hi[32], lo[32];
    #pragma unroll
    for (int j = 0; j < 32; ++j) {
        float v = S[stepl * 32 + j][nl];
        split_bf16(v, hi[j], lo[j]);
    }
    ushort* oh = WPH + ((size_t)gstep * FOUT + n0 + nl) * 32;
    ushort* ol = WPL + ((size_t)gstep * FOUT + n0 + nl) * 32;
    #pragma unroll
    for (int q = 0; q < 4; ++q) {
        u16x8 vh, vl;
        #pragma unroll
        for (int e = 0; e < 8; ++e) { vh[e] = hi[q * 8 + e]; vl[e] = lo[q * 8 + e]; }
        *(u16x8*)(oh + q * 8) = vh;
        *(u16x8*)(ol + q * 8) = vl;
    }
}

// ---------------- MFMA GEMM: part[kz] += Ahi/lo @ Whi/lo ----------------
// block: 64 (M) x 128 (N), 4 waves (wave tile 32x64), K-chunk 1024
__global__ __launch_bounds__(256) void gemm_mfma(
    const ushort* __restrict__ APH, const ushort* __restrict__ APL,
    const ushort* __restrict__ WPH, const ushort* __restrict__ WPL,
    float* __restrict__ part)
{
    __shared__ ushort Ah[64 * LDSPAD], Al[64 * LDSPAD];
    __shared__ ushort Bh[128 * LDSPAD], Bl[128 * LDSPAD];

    int t = threadIdx.x;
    int n0 = blockIdx.x * 128;
    int m0 = blockIdx.y * 64;
    int kz = blockIdx.z;

    int w = t >> 6, l = t & 63;
    int wm = w & 1, wn = w >> 1;     // wave grid 2(M) x 2(N)
    int lane16 = l & 15, kg = l >> 4;

    f32x4 acc[2][4];
    #pragma unroll
    for (int i = 0; i < 2; ++i)
        #pragma unroll
        for (int j = 0; j < 4; ++j) acc[i][j] = (f32x4){0.f, 0.f, 0.f, 0.f};

    int ar = t >> 2, ac = (t & 3);   // A: 256 slots of 16B
    int stepbase = kz * CH_STEPS;

    u32x4 ra_h, ra_l, rb_h0, rb_h1, rb_l0, rb_l1;

#define LOADS(s_)                                                                  \
    {                                                                              \
        size_t sa = ((size_t)(stepbase + (s_)) * M_PAD + m0) * 32;                 \
        size_t sb = ((size_t)(stepbase + (s_)) * FOUT + n0) * 32;                  \
        ra_h  = *(const u32x4*)(APH + sa + t * 8);                                 \
        ra_l  = *(const u32x4*)(APL + sa + t * 8);                                 \
        rb_h0 = *(const u32x4*)(WPH + sb + t * 8);                                 \
        rb_h1 = *(const u32x4*)(WPH + sb + (t + 256) * 8);                         \
        rb_l0 = *(const u32x4*)(WPL + sb + t * 8);                                 \
        rb_l1 = *(const u32x4*)(WPL + sb + (t + 256) * 8);                         \
    }

    LOADS(0);
    for (int s = 0; s < CH_STEPS; ++s) {
        __syncthreads();
        *(u32x4*)&Ah[ar * LDSPAD + ac * 8] = ra_h;
        *(u32x4*)&Al[ar * LDSPAD + ac * 8] = ra_l;
        *(u32x4*)&Bh[ar * LDSPAD + ac * 8] = rb_h0;
        *(u32x4*)&Bh[(ar + 64) * LDSPAD + ac * 8] = rb_h1;
        *(u32x4*)&Bl[ar * LDSPAD + ac * 8] = rb_l0;
        *(u32x4*)&Bl[(ar + 64) * LDSPAD + ac * 8] = rb_l1;
        __syncthreads();
        if (s + 1 < CH_STEPS) LOADS(s + 1);

        bf16x8 a_h[2], a_l[2], b_h[4], b_l[4];
        #pragma unroll
        for (int mi = 0; mi < 2; ++mi) {
            int m = wm * 32 + mi * 16 + lane16;
            a_h[mi] = *(bf16x8*)&Ah[m * LDSPAD + kg * 8];
            a_l[mi] = *(bf16x8*)&Al[m * LDSPAD + kg * 8];
        }
        #pragma unroll
        for (int ni = 0; ni < 4; ++ni) {
            int n = wn * 64 + ni * 16 + lane16;
            b_h[ni] = *(bf16x8*)&Bh[n * LDSPAD + kg * 8];
            b_l[ni] = *(bf16x8*)&Bl[n * LDSPAD + kg * 8];
        }
        #pragma unroll
        for (int mi = 0; mi < 2; ++mi)
            #pragma unroll
            for (int ni = 0; ni < 4; ++ni) {
                acc[mi][ni] = __builtin_amdgcn_mfma_f32_16x16x32_bf16(a_h[mi], b_h[ni], acc[mi][ni], 0, 0, 0);
                acc[mi][ni] = __builtin_amdgcn_mfma_f32_16x16x32_bf16(a_h[mi], b_l[ni], acc[mi][ni], 0, 0, 0);
                acc[mi][ni] = __builtin_amdgcn_mfma_f32_16x16x32_bf16(a_l[mi], b_h[ni], acc[mi][ni], 0, 0, 0);
            }
    }
#undef LOADS

    // epilogue: C/D layout col = lane&15, row = (lane>>4)*4 + reg
    #pragma unroll
    for (int mi = 0; mi < 2; ++mi)
        #pragma unroll
        for (int ni = 0; ni < 4; ++ni)
            #pragma unroll
            for (int r = 0; r < 4; ++r) {
                int m = m0 + wm * 32 + mi * 16 + kg * 4 + r;
                if (m < BP) {
                    int n = n0 + wn * 64 + ni * 16 + lane16;
                    part[((size_t)kz * BP + m) * FOUT + n] = acc[mi][ni][r];
                }
            }
}

// ---------------- MLP (fused partial-reduce) + softmax ----------------
__global__ __launch_bounds__(256) void mlp2(
    const float* __restrict__ part,
    const float* __restrict__ bfeat,
    const float* __restrict__ W1, const float* __restrict__ b1,
    const float* __restrict__ W2, const float* __restrict__ b2,
    float* __restrict__ probs, float* __restrict__ logits_ws)
{
    __shared__ float sf[2][FOUT];
    __shared__ float sh[2][HID];
    __shared__ float sl[2][NG];
    int r0 = blockIdx.x * 2;
    int t = threadIdx.x;
    for (int i = t; i < 2 * FOUT; i += 256) {
        int r = i / FOUT, c = i - r * FOUT;
        size_t idx = (size_t)(r0 + r) * FOUT + c;
        float v = bfeat[c] + part[idx] + part[idx + (size_t)BP * FOUT]
                + part[idx + (size_t)2 * BP * FOUT] + part[idx + (size_t)3 * BP * FOUT];
        sf[r][c] = v;
    }
    __syncthreads();
    {
        int r = t >> 7, j = t & 127;
        float acc = b1[j];
        #pragma unroll 8
        for (int k = 0; k < FOUT; ++k)
            acc = fmaf(sf[r][k], W1[(size_t)k * HID + j], acc);
        sh[r][j] = fmaxf(acc, 0.0f);
    }
    __syncthreads();
    if (t < 6) {
        int rr = t / 3, c = t - rr * 3;
        float a = b2[c];
        #pragma unroll 16
        for (int k = 0; k < HID; ++k) a = fmaf(sh[rr][k], W2[k * NG + c], a);
        sl[rr][c] = a;
        logits_ws[(r0 + rr) * NG + c] = a;
    }
    __syncthreads();
    if (t < 2) {
        float l0 = sl[t][0], l1 = sl[t][1], l2 = sl[t][2];
        float m = fmaxf(l0, fmaxf(l1, l2));
        float e0 = expf(l0 - m), e1 = expf(l1 - m), e2 = expf(l2 - m);
        float inv = 1.0f / (e0 + e1 + e2);
        int row = r0 + t;
        probs[row * NG + 0] = e0 * inv;
        probs[row * NG + 1] = e1 * inv;
        probs[row * NG + 2] = e2 * inv;
    }
}

// ---------------- grade loss ----------------
__global__ __launch_bounds__(512) void loss_kernel(
    const float* __restrict__ logits,
    const int* __restrict__ grade,
    float* __restrict__ out0)
{
    __shared__ float snum[512];
    __shared__ float sden[512];
    int t = threadIdx.x;
    float num = 0.0f, den = 0.0f;
    for (int p = t; p < BP; p += 512) {
        int g = grade[p];
        float lv = logits[p * NG + g];
        lv = fminf(fmaxf(lv, 1e-5f), 1.0f - 1e-5f);
        float wt = (g == 0) ? 1.0f : (g == 1 ? 2.0f : 4.0f);
        num += wt * logf(lv);
        den += wt;
    }
    snum[t] = num; sden[t] = den;
    __syncthreads();
    for (int s = 256; s > 0; s >>= 1) {
        if (t < s) { snum[t] += snum[t + s]; sden[t] += sden[t + s]; }
        __syncthreads();
    }
    if (t == 0) out0[0] = -snum[0] / sden[0];
}

// ================= fallback (round-1, known-good) =================
__global__ __launch_bounds__(256) void crops_kernel(
    const float* __restrict__ images,
    const float* __restrict__ z_pred,
    const float* __restrict__ xy_pred,
    float* __restrict__ crop)
{
    int pt = blockIdx.x;
    int b  = pt / P_;
    int z = (int)rintf(z_pred[pt] - 1.0f);
    z = min(max(z, 0), D_SL_ - 1);
    int x = (int)rintf(4.0f * xy_pred[pt * 2 + 0]);
    int y = (int)rintf(4.0f * xy_pred[pt * 2 + 1]);
    x = min(max(x, 0), W_ - 1);
    y = min(max(y, 0), H_ - 1);
    const float* img = images + (size_t)(b * D_SL_ + z) * (H_ * W_);
    for (int i = threadIdx.x; i < C_ * C_; i += 256) {
        int r = i >> 6, c = i & 63;
        int iy = y - 32 + r;
        int ix = x - 32 + c;
        float v = 0.0f;
        if ((unsigned)iy < (unsigned)H_ && (unsigned)ix < (unsigned)W_)
            v = img[iy * W_ + ix];
        crop[(size_t)pt * KPIX + i] = v;
    }
}

#define KC 32
__global__ __launch_bounds__(256) void gemm_kernel(
    const float* __restrict__ crop,
    const float* __restrict__ Wf,
    const float* __restrict__ bf,
    float* __restrict__ feats)
{
    __shared__ float As[KC][C_];
    __shared__ float Bs[KC][68];
    int n0 = blockIdx.x * 64;
    int m0 = blockIdx.y * 64;
    int t  = threadIdx.x;
    float acc[4][4];
    #pragma unroll
    for (int i = 0; i < 4; ++i)
        #pragma unroll
        for (int j = 0; j < 4; ++j) acc[i][j] = 0.0f;
    int tm = (t >> 4) << 2;
    int tn = (t & 15) << 2;
    for (int k0 = 0; k0 < KPIX; k0 += KC) {
        #pragma unroll
        for (int i = 0; i < 2; ++i) {
            int idx = t + i * 256;
            int row = idx >> 3;
            int kq  = (idx & 7) << 2;
            int m = m0 + row;
            float4 v = make_float4(0.f, 0.f, 0.f, 0.f);
            if (m < BP) v = *(const float4*)(crop + (size_t)m * KPIX + k0 + kq);
            As[kq + 0][row] = v.x; As[kq + 1][row] = v.y;
            As[kq + 2][row] = v.z; As[kq + 3][row] = v.w;
        }
        #pragma unroll
        for (int i = 0; i < 2; ++i) {
            int idx = t + i * 256;
            int row = idx >> 4;
            int nq  = (idx & 15) << 2;
            const float* base = Wf + (size_t)(k0 + row) * FOUT + n0 + nq;
            float4 a  = *(const float4*)(base);
            float4 b4 = *(const float4*)(base + (size_t)KPIX * FOUT);
            float4 c4 = *(const float4*)(base + (size_t)2 * KPIX * FOUT);
            *(float4*)&Bs[row][nq] = make_float4(a.x + b4.x + c4.x, a.y + b4.y + c4.y,
                                                 a.z + b4.z + c4.z, a.w + b4.w + c4.w);
        }
        __syncthreads();
        #pragma unroll 8
        for (int k = 0; k < KC; ++k) {
            float4 av = *(const float4*)&As[k][tm];
            float4 bv = *(const float4*)&Bs[k][tn];
            acc[0][0] = fmaf(av.x, bv.x, acc[0][0]); acc[0][1] = fmaf(av.x, bv.y, acc[0][1]);
            acc[0][2] = fmaf(av.x, bv.z, acc[0][2]); acc[0][3] = fmaf(av.x, bv.w, acc[0][3]);
            acc[1][0] = fmaf(av.y, bv.x, acc[1][0]); acc[1][1] = fmaf(av.y, bv.y, acc[1][1]);
            acc[1][2] = fmaf(av.y, bv.z, acc[1][2]); acc[1][3] = fmaf(av.y, bv.w, acc[1][3]);
            acc[2][0] = fmaf(av.z, bv.x, acc[2][0]); acc[2][1] = fmaf(av.z, bv.y, acc[2][1]);
            acc[2][2] = fmaf(av.z, bv.z, acc[2][2]); acc[2][3] = fmaf(av.z, bv.w, acc[2][3]);
            acc[3][0] = fmaf(av.w, bv.x, acc[3][0]); acc[3][1] = fmaf(av.w, bv.y, acc[3][1]);
            acc[3][2] = fmaf(av.w, bv.z, acc[3][2]); acc[3][3] = fmaf(av.w, bv.w, acc[3][3]);
        }
        __syncthreads();
    }
    #pragma unroll
    for (int i = 0; i < 4; ++i) {
        int m = m0 + tm + i;
        if (m >= BP) break;
        int n = n0 + tn;
        float4 bb = *(const float4*)(bf + n);
        float4 o = make_float4(acc[i][0] + bb.x, acc[i][1] + bb.y,
                               acc[i][2] + bb.z, acc[i][3] + bb.w);
        *(float4*)(feats + (size_t)m * FOUT + n) = o;
    }
}

__global__ __launch_bounds__(256) void mlp_kernel(
    const float* __restrict__ feats,
    const float* __restrict__ W1, const float* __restrict__ b1,
    const float* __restrict__ W2, const float* __restrict__ b2,
    float* __restrict__ probs_out,
    float* __restrict__ logits_ws)
{
    __shared__ float sf[8][FOUT];
    __shared__ float sh[8][HID];
    int r0 = blockIdx.x * 8;
    int t  = threadIdx.x;
    for (int i = t; i < 8 * FOUT; i += 256) {
        int r = i / FOUT;
        int c = i - r * FOUT;
        sf[r][c] = feats[(size_t)(r0 + r) * FOUT + c];
    }
    __syncthreads();
    int r  = t >> 5;
    int j0 = t & 31;
    float a0 = b1[j0], a1 = b1[j0 + 32], a2 = b1[j0 + 64], a3 = b1[j0 + 96];
    #pragma unroll 4
    for (int k = 0; k < FOUT; ++k) {
        float a = sf[r][k];
        const float* wp = W1 + (size_t)k * HID + j0;
        a0 = fmaf(a, wp[0],  a0);
        a1 = fmaf(a, wp[32], a1);
        a2 = fmaf(a, wp[64], a2);
        a3 = fmaf(a, wp[96], a3);
    }
    sh[r][j0]      = fmaxf(a0, 0.0f);
    sh[r][j0 + 32] = fmaxf(a1, 0.0f);
    sh[r][j0 + 64] = fmaxf(a2, 0.0f);
    sh[r][j0 + 96] = fmaxf(a3, 0.0f);
    __syncthreads();
    if (t < 8) {
        float lv[NG];
        #pragma unroll
        for (int c = 0; c < NG; ++c) {
            float acc = b2[c];
            for (int j = 0; j < HID; ++j)
                acc = fmaf(sh[t][j], W2[j * NG + c], acc);
            lv[c] = acc;
        }
        int row = r0 + t;
        logits_ws[row * NG + 0] = lv[0];
        logits_ws[row * NG + 1] = lv[1];
        logits_ws[row * NG + 2] = lv[2];
        float m = fmaxf(lv[0], fmaxf(lv[1], lv[2]));
        float e0 = expf(lv[0] - m), e1 = expf(lv[1] - m), e2 = expf(lv[2] - m);
        float inv = 1.0f / (e0 + e1 + e2);
        probs_out[row * NG + 0] = e0 * inv;
        probs_out[row * NG + 1] = e1 * inv;
        probs_out[row * NG + 2] = e2 * inv;
    }
}

// ---------------- launch ----------------
extern "C" void kernel_launch(void* const* d_in, const int* in_sizes, int n_in,
                              void* d_out, int out_size, void* d_ws, size_t ws_size,
                              hipStream_t stream) {
    const float* images  = (const float*)d_in[0];
    const float* z_pred  = (const float*)d_in[1];
    const float* xy_pred = (const float*)d_in[2];
    const int*   grade   = (const int*)d_in[3];
    const float* W_feat  = (const float*)d_in[4];
    const float* b_feat  = (const float*)d_in[5];
    const float* W1      = (const float*)d_in[6];
    const float* b1      = (const float*)d_in[7];
    const float* W2      = (const float*)d_in[8];
    const float* b2      = (const float*)d_in[9];

    float* out = (float*)d_out;

    if (ws_size >= (size_t)WS_NEED) {
        char* w = (char*)d_ws;
        ushort* APH = (ushort*)(w + OFF_APH);
        ushort* APL = (ushort*)(w + OFF_APL);
        ushort* WPH = (ushort*)(w + OFF_WPH);
        ushort* WPL = (ushort*)(w + OFF_WPL);
        float*  part   = (float*)(w + OFF_PART);
        float*  logits = (float*)(w + OFF_LOG);

        crops_split<<<BP, 128, 0, stream>>>(images, z_pred, xy_pred, APH, APL);
        prep_w<<<dim3(32, 20), 256, 0, stream>>>(W_feat, WPH, WPL);
        gemm_mfma<<<dim3(10, 7, KSPL), 256, 0, stream>>>(APH, APL, WPH, WPL, part);
        mlp2<<<BP / 2, 256, 0, stream>>>(part, b_feat, W1, b1, W2, b2, out + 1, logits);
        loss_kernel<<<1, 512, 0, stream>>>(logits, grade, out);
    } else {
        float* ws = (float*)d_ws;
        float* crop   = ws;
        float* feats  = ws + (size_t)BP * KPIX;
        float* logits = feats + (size_t)BP * FOUT;

        crops_kernel<<<BP, 256, 0, stream>>>(images, z_pred, xy_pred, crop);
        gemm_kernel<<<dim3(FOUT / 64, (BP + 63) / 64), 256, 0, stream>>>(crop, W_feat, b_feat, feats);
        mlp_kernel<<<BP / 8, 256, 0, stream>>>(feats, W1, b1, W2, b2, out + 1, logits);
        loss_kernel<<<1, 512, 0, stream>>>(logits, grade, out);
    }
}

// Round 3
// 117.772 us; speedup vs baseline: 3.0687x; 1.0155x over previous
//
#include <hip/hip_runtime.h>
#include <hip/hip_bf16.h>
#include <math.h>

#define B_    16
#define P_    25
#define D_SL_ 32
#define H_    320
#define W_    320
#define BP    400
#define KPIX  4096
#define FOUT  1280
#define HID   128
#define NG    3

// gemm geometry
#define M_PAD    512         // 4 m-tiles of 128
#define NSTEPS   128         // 4096 / 32
#define KSPL     8           // k-chunks
#define CH_STEPS 16          // 32-wide k-steps per chunk

typedef __attribute__((ext_vector_type(8))) short  bf16x8;
typedef __attribute__((ext_vector_type(8))) ushort u16x8;
typedef __attribute__((ext_vector_type(4))) float  f32x4;
typedef __attribute__((ext_vector_type(4))) unsigned int u32x4;
typedef unsigned long long ull;

// ws byte offsets
#define OFF_APH  0ull
#define OFF_APL  4194304ull      // 128*512*32*2
#define OFF_WPH  8388608ull
#define OFF_WPL  18874368ull     // + 128*1280*32*2
#define OFF_PART 29360128ull
#define WS_NEED  (29360128ull + (ull)KSPL * BP * FOUT * 4ull)

__device__ inline void split_bf16(float x, ushort& hi, ushort& lo) {
    __hip_bfloat16 h = __float2bfloat16(x);
    float hf = __bfloat162float(h);
    __hip_bfloat16 l = __float2bfloat16(x - hf);
    hi = *(ushort*)&h;
    lo = *(ushort*)&l;
}

// ---------------- crops -> paneled bf16 hi/lo  [step][M_PAD][32] ----------------
__global__ __launch_bounds__(128) void crops_split(
    const float* __restrict__ images,
    const float* __restrict__ z_pred,
    const float* __restrict__ xy_pred,
    ushort* __restrict__ APH, ushort* __restrict__ APL)
{
    int pt = blockIdx.x;             // 0..511 (>=400 -> zero rows)
    int t = threadIdx.x;             // k-step index 0..127
    ushort* oh = APH + ((size_t)t * M_PAD + pt) * 32;
    ushort* ol = APL + ((size_t)t * M_PAD + pt) * 32;

    if (pt >= BP) {
        u16x8 z = (u16x8)0;
        #pragma unroll
        for (int q = 0; q < 4; ++q) { *(u16x8*)(oh + q * 8) = z; *(u16x8*)(ol + q * 8) = z; }
        return;
    }

    int b  = pt / P_;
    int z = (int)rintf(z_pred[pt] - 1.0f);
    z = min(max(z, 0), D_SL_ - 1);
    int x = (int)rintf(4.0f * xy_pred[pt * 2 + 0]);
    int y = (int)rintf(4.0f * xy_pred[pt * 2 + 1]);
    x = min(max(x, 0), W_ - 1);
    y = min(max(y, 0), H_ - 1);
    const float* img = images + (size_t)(b * D_SL_ + z) * (H_ * W_);

    int r = t >> 1;                  // crop row 0..63
    int cb = (t & 1) * 32;           // crop col base
    int iy = y - 32 + r;
    bool vy = (iy >= 0) && (iy < H_);
    int iyc = min(max(iy, 0), H_ - 1);
    const float* row = img + (size_t)iyc * W_;

    ushort hi[32], lo[32];
    #pragma unroll
    for (int j = 0; j < 32; ++j) {
        int ix = x - 32 + cb + j;
        float v = 0.0f;
        if (vy && ix >= 0 && ix < W_) v = row[ix];
        split_bf16(v, hi[j], lo[j]);
    }
    #pragma unroll
    for (int q = 0; q < 4; ++q) {
        u16x8 vh, vl;
        #pragma unroll
        for (int e = 0; e < 8; ++e) { vh[e] = hi[q * 8 + e]; vl[e] = lo[q * 8 + e]; }
        *(u16x8*)(oh + q * 8) = vh;
        *(u16x8*)(ol + q * 8) = vl;
    }
}

// ---------------- Wsum -> paneled bf16 hi/lo [step][1280][32] ----------------
__global__ __launch_bounds__(256) void prep_w(
    const float* __restrict__ Wf,
    ushort* __restrict__ WPH, ushort* __restrict__ WPL)
{
    __shared__ float S[128][68];
    int t = threadIdx.x;
    int k0 = blockIdx.x * 128;       // 32 blocks
    int n0 = blockIdx.y * 64;        // 20 blocks
    #pragma unroll
    for (int p = 0; p < 8; ++p) {
        int kl = p * 16 + (t >> 4);
        int nq = (t & 15) * 4;
        const float* base = Wf + (size_t)(k0 + kl) * FOUT + n0 + nq;
        float4 a = *(const float4*)base;
        float4 b = *(const float4*)(base + (size_t)KPIX * FOUT);
        float4 c = *(const float4*)(base + (size_t)2 * KPIX * FOUT);
        *(float4*)&S[kl][nq] = make_float4(a.x + b.x + c.x, a.y + b.y + c.y,
                                           a.z + b.z + c.z, a.w + b.w + c.w);
    }
    __syncthreads();
    int stepl = t >> 6;              // 0..3
    int nl = t & 63;
    int gstep = blockIdx.x * 4 + stepl;
    ushort hi[32], lo[32];
    #pragma unroll
    for (int j = 0; j < 32; ++j) {
        float v = S[stepl * 32 + j][nl];
        split_bf16(v, hi[j], lo[j]);
    }
    ushort* oh = WPH + ((size_t)gstep * FOUT + n0 + nl) * 32;
    ushort* ol = WPL + ((size_t)gstep * FOUT + n0 + nl) * 32;
    #pragma unroll
    for (int q = 0; q < 4; ++q) {
        u16x8 vh, vl;
        #pragma unroll
        for (int e = 0; e < 8; ++e) { vh[e] = hi[q * 8 + e]; vl[e] = lo[q * 8 + e]; }
        *(u16x8*)(oh + q * 8) = vh;
        *(u16x8*)(ol + q * 8) = vl;
    }
}

// ---------------- MFMA GEMM v2 ----------------
// block 128(M)x128(N), 4 waves (2x2), wave tile 64x64 = 4x4 of 16x16x32 frags.
// LDS rows 128B = [hi 64B | lo 64B], 8B-unit XOR swizzle (unit ^= row&15).
__global__ __launch_bounds__(256) void gemm_mfma(
    const ushort* __restrict__ APH, const ushort* __restrict__ APL,
    const ushort* __restrict__ WPH, const ushort* __restrict__ WPL,
    float* __restrict__ part, float* __restrict__ out0)
{
    __shared__ ushort Atile[128 * 64];   // 16 KB, row r: 64 ushorts
    __shared__ ushort Btile[128 * 64];   // 16 KB

    int t = threadIdx.x;
    int n0 = blockIdx.x * 128;
    int m0 = blockIdx.y * 128;
    int kz = blockIdx.z;
    int stepbase = kz * CH_STEPS;

    if (blockIdx.x == 0 && blockIdx.y == 0 && kz == 0 && t == 0) out0[0] = 0.0f;

    int w = t >> 6, l = t & 63;
    int wm = w & 1, wn = w >> 1;
    int l16 = l & 15, kg = l >> 4;      // kg 0..3

    f32x4 acc[4][4];
    #pragma unroll
    for (int i = 0; i < 4; ++i)
        #pragma unroll
        for (int j = 0; j < 4; ++j) acc[i][j] = (f32x4){0.f, 0.f, 0.f, 0.f};

    // staging: thread t covers row tr = t>>1 of A and B tiles, half (t&1): 0=hi,1=lo
    int tr = t >> 1;
    int hb = (t & 1) * 8;               // unit base within the 16-unit row
    int rm = tr & 15;

    u32x4 preA[4], preB[4];

#define LOADS(s_)                                                                   \
    {                                                                               \
        const ushort* asrc = ((t & 1) ? APL : APH)                                  \
            + ((size_t)(stepbase + (s_)) * M_PAD + m0 + tr) * 32;                   \
        const ushort* bsrc = ((t & 1) ? WPL : WPH)                                  \
            + ((size_t)(stepbase + (s_)) * FOUT + n0 + tr) * 32;                    \
        preA[0] = ((const u32x4*)asrc)[0]; preA[1] = ((const u32x4*)asrc)[1];       \
        preA[2] = ((const u32x4*)asrc)[2]; preA[3] = ((const u32x4*)asrc)[3];       \
        preB[0] = ((const u32x4*)bsrc)[0]; preB[1] = ((const u32x4*)bsrc)[1];       \
        preB[2] = ((const u32x4*)bsrc)[2]; preB[3] = ((const u32x4*)bsrc)[3];       \
    }

    LOADS(0);
    for (int s = 0; s < CH_STEPS; ++s) {
        __syncthreads();
        {
            ushort* arow = &Atile[tr * 64];
            ushort* brow = &Btile[tr * 64];
            #pragma unroll
            for (int q = 0; q < 4; ++q) {
                #pragma unroll
                for (int h = 0; h < 2; ++h) {
                    int j = q * 2 + h;
                    int u = (hb + j) ^ rm;
                    *(ull*)&arow[u * 4] = ((const ull*)&preA[q])[h];
                    *(ull*)&brow[u * 4] = ((const ull*)&preB[q])[h];
                }
            }
        }
        __syncthreads();
        if (s + 1 < CH_STEPS) LOADS(s + 1);

        union FragU { ull q[2]; bf16x8 v; };
        bf16x8 ah[4], al[4], bh[4], bl[4];
        #pragma unroll
        for (int mi = 0; mi < 4; ++mi) {
            int r = wm * 64 + mi * 16 + l16;
            const ushort* rowp = &Atile[r * 64];
            FragU fh, fl;
            fh.q[0] = *(const ull*)&rowp[(((2 * kg) ^ l16)) * 4];
            fh.q[1] = *(const ull*)&rowp[(((2 * kg + 1) ^ l16)) * 4];
            fl.q[0] = *(const ull*)&rowp[(((8 + 2 * kg) ^ l16)) * 4];
            fl.q[1] = *(const ull*)&rowp[(((9 + 2 * kg) ^ l16)) * 4];
            ah[mi] = fh.v; al[mi] = fl.v;
        }
        #pragma unroll
        for (int ni = 0; ni < 4; ++ni) {
            int r = wn * 64 + ni * 16 + l16;
            const ushort* rowp = &Btile[r * 64];
            FragU fh, fl;
            fh.q[0] = *(const ull*)&rowp[(((2 * kg) ^ l16)) * 4];
            fh.q[1] = *(const ull*)&rowp[(((2 * kg + 1) ^ l16)) * 4];
            fl.q[0] = *(const ull*)&rowp[(((8 + 2 * kg) ^ l16)) * 4];
            fl.q[1] = *(const ull*)&rowp[(((9 + 2 * kg) ^ l16)) * 4];
            bh[ni] = fh.v; bl[ni] = fl.v;
        }
        #pragma unroll
        for (int mi = 0; mi < 4; ++mi)
            #pragma unroll
            for (int ni = 0; ni < 4; ++ni) {
                acc[mi][ni] = __builtin_amdgcn_mfma_f32_16x16x32_bf16(ah[mi], bh[ni], acc[mi][ni], 0, 0, 0);
                acc[mi][ni] = __builtin_amdgcn_mfma_f32_16x16x32_bf16(ah[mi], bl[ni], acc[mi][ni], 0, 0, 0);
                acc[mi][ni] = __builtin_amdgcn_mfma_f32_16x16x32_bf16(al[mi], bh[ni], acc[mi][ni], 0, 0, 0);
            }
    }
#undef LOADS

    // epilogue: C/D row = kg*4 + reg, col = l16 (verified r2)
    #pragma unroll
    for (int mi = 0; mi < 4; ++mi)
        #pragma unroll
        for (int ni = 0; ni < 4; ++ni)
            #pragma unroll
            for (int r = 0; r < 4; ++r) {
                int m = m0 + wm * 64 + mi * 16 + kg * 4 + r;
                if (m < BP) {
                    int n = n0 + wn * 64 + ni * 16 + l16;
                    part[((size_t)kz * BP + m) * FOUT + n] = acc[mi][ni][r];
                }
            }
}

// ---------------- MLP + softmax + fused loss ----------------
__global__ __launch_bounds__(256) void mlp2_loss(
    const float* __restrict__ part,
    const float* __restrict__ bfeat,
    const float* __restrict__ W1, const float* __restrict__ b1,
    const float* __restrict__ W2, const float* __restrict__ b2,
    const int* __restrict__ grade,
    float* __restrict__ probs, float* __restrict__ out0)
{
    __shared__ float sf[2][FOUT];
    __shared__ float sh[2][HID];
    __shared__ float sl[2][NG];
    __shared__ float sden[256];
    int r0 = blockIdx.x * 2;
    int t = threadIdx.x;

    // global weight denominator (same in every block; deterministic)
    float dwt = 0.0f;
    for (int p = t; p < BP; p += 256) {
        int g = grade[p];
        dwt += (g == 0) ? 1.0f : (g == 1 ? 2.0f : 4.0f);
    }
    sden[t] = dwt;

    for (int i = t; i < 2 * FOUT; i += 256) {
        int r = i / FOUT, c = i - r * FOUT;
        size_t base = (size_t)(r0 + r) * FOUT + c;
        float v = bfeat[c];
        #pragma unroll
        for (int kzi = 0; kzi < KSPL; ++kzi)
            v += part[(size_t)kzi * BP * FOUT + base];
        sf[r][c] = v;
    }
    __syncthreads();
    for (int sft = 128; sft > 0; sft >>= 1) {
        if (t < sft) sden[t] += sden[t + sft];
        __syncthreads();
    }
    float den = sden[0];

    {
        int r = t >> 7, j = t & 127;
        float acc = b1[j];
        #pragma unroll 8
        for (int k = 0; k < FOUT; ++k)
            acc = fmaf(sf[r][k], W1[(size_t)k * HID + j], acc);
        sh[r][j] = fmaxf(acc, 0.0f);
    }
    __syncthreads();
    if (t < 6) {
        int rr = t / 3, c = t - rr * 3;
        float a = b2[c];
        #pragma unroll 16
        for (int k = 0; k < HID; ++k) a = fmaf(sh[rr][k], W2[k * NG + c], a);
        sl[rr][c] = a;
    }
    __syncthreads();
    if (t < 2) {
        float l0 = sl[t][0], l1 = sl[t][1], l2 = sl[t][2];
        float m = fmaxf(l0, fmaxf(l1, l2));
        float e0 = expf(l0 - m), e1 = expf(l1 - m), e2 = expf(l2 - m);
        float inv = 1.0f / (e0 + e1 + e2);
        int row = r0 + t;
        probs[row * NG + 0] = e0 * inv;
        probs[row * NG + 1] = e1 * inv;
        probs[row * NG + 2] = e2 * inv;

        int g = grade[row];
        float lv = (g == 0) ? l0 : (g == 1 ? l1 : l2);
        lv = fminf(fmaxf(lv, 1e-5f), 1.0f - 1e-5f);
        float wt = (g == 0) ? 1.0f : (g == 1 ? 2.0f : 4.0f);
        atomicAdd(out0, -(wt * logf(lv)) / den);
    }
}

// ---------------- launch ----------------
extern "C" void kernel_launch(void* const* d_in, const int* in_sizes, int n_in,
                              void* d_out, int out_size, void* d_ws, size_t ws_size,
                              hipStream_t stream) {
    const float* images  = (const float*)d_in[0];
    const float* z_pred  = (const float*)d_in[1];
    const float* xy_pred = (const float*)d_in[2];
    const int*   grade   = (const int*)d_in[3];
    const float* W_feat  = (const float*)d_in[4];
    const float* b_feat  = (const float*)d_in[5];
    const float* W1      = (const float*)d_in[6];
    const float* b1      = (const float*)d_in[7];
    const float* W2      = (const float*)d_in[8];
    const float* b2      = (const float*)d_in[9];

    float* out = (float*)d_out;
    char* w = (char*)d_ws;
    ushort* APH = (ushort*)(w + OFF_APH);
    ushort* APL = (ushort*)(w + OFF_APL);
    ushort* WPH = (ushort*)(w + OFF_WPH);
    ushort* WPL = (ushort*)(w + OFF_WPL);
    float*  part = (float*)(w + OFF_PART);

    crops_split<<<M_PAD, 128, 0, stream>>>(images, z_pred, xy_pred, APH, APL);
    prep_w<<<dim3(32, 20), 256, 0, stream>>>(W_feat, WPH, WPL);
    gemm_mfma<<<dim3(10, 4, KSPL), 256, 0, stream>>>(APH, APL, WPH, WPL, part, out);
    mlp2_loss<<<BP / 2, 256, 0, stream>>>(part, b_feat, W1, b1, W2, b2, grade, out + 1, out);
}

// Round 4
// 79.451 us; speedup vs baseline: 4.5488x; 1.4823x over previous
//
#include <hip/hip_runtime.h>
#include <hip/hip_bf16.h>
#include <math.h>

#define B_    16
#define P_    25
#define D_SL_ 32
#define H_    320
#define W_    320
#define BP    400
#define KPIX  4096
#define FOUT  1280
#define HID   128
#define NG    3

// gemm geometry
#define M_PAD    512         // 4 m-tiles of 128
#define NSTEPS   128         // 4096 / 32
#define KSPL     8           // k-chunks
#define CH_STEPS 16          // 32-wide k-steps per chunk

#define CROP_BLOCKS 512      // fused_prep: blocks [0,512) crops, [512,1152) prep_w

typedef __attribute__((ext_vector_type(8))) short  bf16x8;
typedef __attribute__((ext_vector_type(8))) ushort u16x8;
typedef __attribute__((ext_vector_type(4))) float  f32x4;
typedef __attribute__((ext_vector_type(4))) unsigned int u32x4;
typedef unsigned long long ull;

// ws byte offsets
#define OFF_APH  0ull
#define OFF_APL  4194304ull      // 128*512*32*2
#define OFF_WPH  8388608ull
#define OFF_WPL  18874368ull     // + 128*1280*32*2
#define OFF_PART 29360128ull
#define WS_NEED  (29360128ull + (ull)KSPL * BP * FOUT * 4ull)

__device__ inline void split_bf16(float x, ushort& hi, ushort& lo) {
    __hip_bfloat16 h = __float2bfloat16(x);
    float hf = __bfloat162float(h);
    __hip_bfloat16 l = __float2bfloat16(x - hf);
    hi = *(ushort*)&h;
    lo = *(ushort*)&l;
}

// ---------------- fused prep: crops->panels  +  Wsum->panels ----------------
// blocks [0, CROP_BLOCKS): one point each (>=BP -> zero rows).
//   Phase 1: coalesced gather of the 64x64 crop into LDS (lane-per-element).
//   Phase 2: LDS -> split-bf16 panel write [step][M_PAD][32].
// blocks [CROP_BLOCKS, CROP_BLOCKS+640): prep_w, 128k x 64n chunk each.
__global__ __launch_bounds__(256) void fused_prep(
    const float* __restrict__ images,
    const float* __restrict__ z_pred,
    const float* __restrict__ xy_pred,
    const float* __restrict__ Wf,
    ushort* __restrict__ APH, ushort* __restrict__ APL,
    ushort* __restrict__ WPH, ushort* __restrict__ WPL)
{
    __shared__ float S[128][68];
    int t = threadIdx.x;

    if (blockIdx.x < CROP_BLOCKS) {
        int pt = blockIdx.x;
        if (pt >= BP) {
            u16x8 z8 = (u16x8)0;
            #pragma unroll
            for (int i = 0; i < 2; ++i) {
                int tau = t + i * 256;
                int step = tau >> 2, q = tau & 3;
                *(u16x8*)(APH + ((size_t)step * M_PAD + pt) * 32 + q * 8) = z8;
                *(u16x8*)(APL + ((size_t)step * M_PAD + pt) * 32 + q * 8) = z8;
            }
            return;
        }
        int b = pt / P_;
        int z = (int)rintf(z_pred[pt] - 1.0f);
        z = min(max(z, 0), D_SL_ - 1);
        int x = (int)rintf(4.0f * xy_pred[pt * 2 + 0]);
        int y = (int)rintf(4.0f * xy_pred[pt * 2 + 1]);
        x = min(max(x, 0), W_ - 1);
        y = min(max(y, 0), H_ - 1);
        const float* img = images + (size_t)(b * D_SL_ + z) * (H_ * W_);

        // phase 1: lanes cover consecutive columns -> coalesced 256B per wave-row
        #pragma unroll
        for (int i = 0; i < 16; ++i) {
            int idx = t + i * 256;
            int r = idx >> 6, c = idx & 63;
            int iy = y - 32 + r, ix = x - 32 + c;
            float v = 0.0f;
            if ((unsigned)iy < (unsigned)H_ && (unsigned)ix < (unsigned)W_)
                v = img[iy * W_ + ix];
            S[r][c] = v;
        }
        __syncthreads();

        // phase 2: panel write (same layout as before)
        #pragma unroll
        for (int i = 0; i < 2; ++i) {
            int tau = t + i * 256;
            int step = tau >> 2, q = tau & 3;
            int r = step >> 1, cb = (step & 1) * 32 + q * 8;
            u16x8 vh, vl;
            #pragma unroll
            for (int e = 0; e < 8; ++e) {
                ushort hi, lo;
                split_bf16(S[r][cb + e], hi, lo);
                vh[e] = hi; vl[e] = lo;
            }
            *(u16x8*)(APH + ((size_t)step * M_PAD + pt) * 32 + q * 8) = vh;
            *(u16x8*)(APL + ((size_t)step * M_PAD + pt) * 32 + q * 8) = vl;
        }
        return;
    }

    // ---- prep_w part ----
    int wb = blockIdx.x - CROP_BLOCKS;   // 0..639
    int k0 = (wb & 31) * 128;
    int n0 = (wb >> 5) * 64;
    #pragma unroll
    for (int p = 0; p < 8; ++p) {
        int kl = p * 16 + (t >> 4);
        int nq = (t & 15) * 4;
        const float* base = Wf + (size_t)(k0 + kl) * FOUT + n0 + nq;
        float4 a = *(const float4*)base;
        float4 b = *(const float4*)(base + (size_t)KPIX * FOUT);
        float4 c = *(const float4*)(base + (size_t)2 * KPIX * FOUT);
        *(float4*)&S[kl][nq] = make_float4(a.x + b.x + c.x, a.y + b.y + c.y,
                                           a.z + b.z + c.z, a.w + b.w + c.w);
    }
    __syncthreads();
    int stepl = t >> 6;              // 0..3
    int nl = t & 63;
    int gstep = (wb & 31) * 4 + stepl;
    ushort hi[32], lo[32];
    #pragma unroll
    for (int j = 0; j < 32; ++j) {
        float v = S[stepl * 32 + j][nl];
        split_bf16(v, hi[j], lo[j]);
    }
    ushort* oh = WPH + ((size_t)gstep * FOUT + n0 + nl) * 32;
    ushort* ol = WPL + ((size_t)gstep * FOUT + n0 + nl) * 32;
    #pragma unroll
    for (int q = 0; q < 4; ++q) {
        u16x8 vh, vl;
        #pragma unroll
        for (int e = 0; e < 8; ++e) { vh[e] = hi[q * 8 + e]; vl[e] = lo[q * 8 + e]; }
        *(u16x8*)(oh + q * 8) = vh;
        *(u16x8*)(ol + q * 8) = vl;
    }
}

// ---------------- MFMA GEMM (unchanged from r3, proven absmax 0.0) ----------------
__global__ __launch_bounds__(256) void gemm_mfma(
    const ushort* __restrict__ APH, const ushort* __restrict__ APL,
    const ushort* __restrict__ WPH, const ushort* __restrict__ WPL,
    float* __restrict__ part, float* __restrict__ out0)
{
    __shared__ ushort Atile[128 * 64];
    __shared__ ushort Btile[128 * 64];

    int t = threadIdx.x;
    int n0 = blockIdx.x * 128;
    int m0 = blockIdx.y * 128;
    int kz = blockIdx.z;
    int stepbase = kz * CH_STEPS;

    if (blockIdx.x == 0 && blockIdx.y == 0 && kz == 0 && t == 0) out0[0] = 0.0f;

    int w = t >> 6, l = t & 63;
    int wm = w & 1, wn = w >> 1;
    int l16 = l & 15, kg = l >> 4;

    f32x4 acc[4][4];
    #pragma unroll
    for (int i = 0; i < 4; ++i)
        #pragma unroll
        for (int j = 0; j < 4; ++j) acc[i][j] = (f32x4){0.f, 0.f, 0.f, 0.f};

    int tr = t >> 1;
    int hb = (t & 1) * 8;
    int rm = tr & 15;

    u32x4 preA[4], preB[4];

#define LOADS(s_)                                                                   \
    {                                                                               \
        const ushort* asrc = ((t & 1) ? APL : APH)                                  \
            + ((size_t)(stepbase + (s_)) * M_PAD + m0 + tr) * 32;                   \
        const ushort* bsrc = ((t & 1) ? WPL : WPH)                                  \
            + ((size_t)(stepbase + (s_)) * FOUT + n0 + tr) * 32;                    \
        preA[0] = ((const u32x4*)asrc)[0]; preA[1] = ((const u32x4*)asrc)[1];       \
        preA[2] = ((const u32x4*)asrc)[2]; preA[3] = ((const u32x4*)asrc)[3];       \
        preB[0] = ((const u32x4*)bsrc)[0]; preB[1] = ((const u32x4*)bsrc)[1];       \
        preB[2] = ((const u32x4*)bsrc)[2]; preB[3] = ((const u32x4*)bsrc)[3];       \
    }

    LOADS(0);
    for (int s = 0; s < CH_STEPS; ++s) {
        __syncthreads();
        {
            ushort* arow = &Atile[tr * 64];
            ushort* brow = &Btile[tr * 64];
            #pragma unroll
            for (int q = 0; q < 4; ++q) {
                #pragma unroll
                for (int h = 0; h < 2; ++h) {
                    int j = q * 2 + h;
                    int u = (hb + j) ^ rm;
                    *(ull*)&arow[u * 4] = ((const ull*)&preA[q])[h];
                    *(ull*)&brow[u * 4] = ((const ull*)&preB[q])[h];
                }
            }
        }
        __syncthreads();
        if (s + 1 < CH_STEPS) LOADS(s + 1);

        union FragU { ull q[2]; bf16x8 v; };
        bf16x8 ah[4], al[4], bh[4], bl[4];
        #pragma unroll
        for (int mi = 0; mi < 4; ++mi) {
            int r = wm * 64 + mi * 16 + l16;
            const ushort* rowp = &Atile[r * 64];
            FragU fh, fl;
            fh.q[0] = *(const ull*)&rowp[(((2 * kg) ^ l16)) * 4];
            fh.q[1] = *(const ull*)&rowp[(((2 * kg + 1) ^ l16)) * 4];
            fl.q[0] = *(const ull*)&rowp[(((8 + 2 * kg) ^ l16)) * 4];
            fl.q[1] = *(const ull*)&rowp[(((9 + 2 * kg) ^ l16)) * 4];
            ah[mi] = fh.v; al[mi] = fl.v;
        }
        #pragma unroll
        for (int ni = 0; ni < 4; ++ni) {
            int r = wn * 64 + ni * 16 + l16;
            const ushort* rowp = &Btile[r * 64];
            FragU fh, fl;
            fh.q[0] = *(const ull*)&rowp[(((2 * kg) ^ l16)) * 4];
            fh.q[1] = *(const ull*)&rowp[(((2 * kg + 1) ^ l16)) * 4];
            fl.q[0] = *(const ull*)&rowp[(((8 + 2 * kg) ^ l16)) * 4];
            fl.q[1] = *(const ull*)&rowp[(((9 + 2 * kg) ^ l16)) * 4];
            bh[ni] = fh.v; bl[ni] = fl.v;
        }
        #pragma unroll
        for (int mi = 0; mi < 4; ++mi)
            #pragma unroll
            for (int ni = 0; ni < 4; ++ni) {
                acc[mi][ni] = __builtin_amdgcn_mfma_f32_16x16x32_bf16(ah[mi], bh[ni], acc[mi][ni], 0, 0, 0);
                acc[mi][ni] = __builtin_amdgcn_mfma_f32_16x16x32_bf16(ah[mi], bl[ni], acc[mi][ni], 0, 0, 0);
                acc[mi][ni] = __builtin_amdgcn_mfma_f32_16x16x32_bf16(al[mi], bh[ni], acc[mi][ni], 0, 0, 0);
            }
    }
#undef LOADS

    #pragma unroll
    for (int mi = 0; mi < 4; ++mi)
        #pragma unroll
        for (int ni = 0; ni < 4; ++ni)
            #pragma unroll
            for (int r = 0; r < 4; ++r) {
                int m = m0 + wm * 64 + mi * 16 + kg * 4 + r;
                if (m < BP) {
                    int n = n0 + wn * 64 + ni * 16 + l16;
                    part[((size_t)kz * BP + m) * FOUT + n] = acc[mi][ni][r];
                }
            }
}

// ---------------- MLP + softmax + fused loss (512 thr, K-split-2 GEMV) ----------------
__global__ __launch_bounds__(512) void mlp2_loss(
    const float* __restrict__ part,
    const float* __restrict__ bfeat,
    const float* __restrict__ W1, const float* __restrict__ b1,
    const float* __restrict__ W2, const float* __restrict__ b2,
    const int* __restrict__ grade,
    float* __restrict__ probs, float* __restrict__ out0)
{
    __shared__ float sf[2][FOUT];
    __shared__ float shp[2][2][HID];   // [khalf][row][j]
    __shared__ float sh[2][HID];
    __shared__ float sl[2][NG];
    __shared__ float sden[512];
    int r0 = blockIdx.x * 2;
    int t = threadIdx.x;

    float dwt = 0.0f;
    for (int p = t; p < BP; p += 512) {
        int g = grade[p];
        dwt += (g == 0) ? 1.0f : (g == 1 ? 2.0f : 4.0f);
    }
    sden[t] = dwt;

    for (int i = t; i < 2 * FOUT; i += 512) {
        int r = i / FOUT, c = i - r * FOUT;
        size_t base = (size_t)(r0 + r) * FOUT + c;
        float v = bfeat[c];
        #pragma unroll
        for (int kzi = 0; kzi < KSPL; ++kzi)
            v += part[(size_t)kzi * BP * FOUT + base];
        sf[r][c] = v;
    }
    __syncthreads();
    for (int s = 256; s > 0; s >>= 1) {
        if (t < s) sden[t] += sden[t + s];
        __syncthreads();
    }
    float den = sden[0];

    {
        int j = t & 127, rid = (t >> 7) & 1, kh = t >> 8;
        float acc = kh ? 0.0f : b1[j];
        const float* wp = W1 + (size_t)(kh * 640) * HID + j;
        const float* sp = &sf[rid][kh * 640];
        #pragma unroll 16
        for (int k = 0; k < 640; ++k)
            acc = fmaf(sp[k], wp[(size_t)k * HID], acc);
        shp[kh][rid][j] = acc;
    }
    __syncthreads();
    if (t < 256) {
        int j = t & 127, rid = t >> 7;
        sh[rid][j] = fmaxf(shp[0][rid][j] + shp[1][rid][j], 0.0f);
    }
    __syncthreads();
    if (t < 6) {
        int rr = t / 3, c = t - rr * 3;
        float a = b2[c];
        #pragma unroll 16
        for (int k = 0; k < HID; ++k) a = fmaf(sh[rr][k], W2[k * NG + c], a);
        sl[rr][c] = a;
    }
    __syncthreads();
    if (t < 2) {
        float l0 = sl[t][0], l1 = sl[t][1], l2 = sl[t][2];
        float m = fmaxf(l0, fmaxf(l1, l2));
        float e0 = expf(l0 - m), e1 = expf(l1 - m), e2 = expf(l2 - m);
        float inv = 1.0f / (e0 + e1 + e2);
        int row = r0 + t;
        probs[row * NG + 0] = e0 * inv;
        probs[row * NG + 1] = e1 * inv;
        probs[row * NG + 2] = e2 * inv;

        int g = grade[row];
        float lv = (g == 0) ? l0 : (g == 1 ? l1 : l2);
        lv = fminf(fmaxf(lv, 1e-5f), 1.0f - 1e-5f);
        float wt = (g == 0) ? 1.0f : (g == 1 ? 2.0f : 4.0f);
        atomicAdd(out0, -(wt * logf(lv)) / den);
    }
}

// ---------------- launch ----------------
extern "C" void kernel_launch(void* const* d_in, const int* in_sizes, int n_in,
                              void* d_out, int out_size, void* d_ws, size_t ws_size,
                              hipStream_t stream) {
    const float* images  = (const float*)d_in[0];
    const float* z_pred  = (const float*)d_in[1];
    const float* xy_pred = (const float*)d_in[2];
    const int*   grade   = (const int*)d_in[3];
    const float* W_feat  = (const float*)d_in[4];
    const float* b_feat  = (const float*)d_in[5];
    const float* W1      = (const float*)d_in[6];
    const float* b1      = (const float*)d_in[7];
    const float* W2      = (const float*)d_in[8];
    const float* b2      = (const float*)d_in[9];

    float* out = (float*)d_out;
    char* w = (char*)d_ws;
    ushort* APH = (ushort*)(w + OFF_APH);
    ushort* APL = (ushort*)(w + OFF_APL);
    ushort* WPH = (ushort*)(w + OFF_WPH);
    ushort* WPL = (ushort*)(w + OFF_WPL);
    float*  part = (float*)(w + OFF_PART);

    fused_prep<<<CROP_BLOCKS + 640, 256, 0, stream>>>(images, z_pred, xy_pred, W_feat,
                                                      APH, APL, WPH, WPL);
    gemm_mfma<<<dim3(10, 4, KSPL), 256, 0, stream>>>(APH, APL, WPH, WPL, part, out);
    mlp2_loss<<<BP / 2, 512, 0, stream>>>(part, b_feat, W1, b1, W2, b2, grade, out + 1, out);
}

// Round 5
// 75.339 us; speedup vs baseline: 4.7971x; 1.0546x over previous
//
#include <hip/hip_runtime.h>
#include <hip/hip_bf16.h>
#include <math.h>

#define B_    16
#define P_    25
#define D_SL_ 32
#define H_    320
#define W_    320
#define BP    400
#define KPIX  4096
#define FOUT  1280
#define HID   128
#define NG    3

// gemm geometry
#define M_PAD    512         // 4 m-tiles of 128
#define NSTEPS   128         // 4096 / 32
#define KSPL     8           // k-chunks
#define CH_STEPS 16          // 32-wide k-steps per chunk

#define CROP_BLOCKS 512      // fused_prep: blocks [0,512) crops, [512,1152) prep_w

typedef __attribute__((ext_vector_type(8))) short  bf16x8;
typedef __attribute__((ext_vector_type(8))) ushort u16x8;
typedef __attribute__((ext_vector_type(4))) float  f32x4;
typedef __attribute__((ext_vector_type(4))) unsigned int u32x4;
typedef unsigned long long ull;

// ws byte offsets
#define OFF_APH  0ull
#define OFF_APL  4194304ull      // 128*512*32*2
#define OFF_WPH  8388608ull
#define OFF_WPL  18874368ull     // + 128*1280*32*2
#define OFF_PART 29360128ull
#define WS_NEED  (29360128ull + (ull)KSPL * BP * FOUT * 4ull)

__device__ inline void split_bf16(float x, ushort& hi, ushort& lo) {
    __hip_bfloat16 h = __float2bfloat16(x);
    float hf = __bfloat162float(h);
    __hip_bfloat16 l = __float2bfloat16(x - hf);
    hi = *(ushort*)&h;
    lo = *(ushort*)&l;
}

// ---------------- fused prep: crops->panels  +  Wsum->panels (unchanged r4) --------
__global__ __launch_bounds__(256) void fused_prep(
    const float* __restrict__ images,
    const float* __restrict__ z_pred,
    const float* __restrict__ xy_pred,
    const float* __restrict__ Wf,
    ushort* __restrict__ APH, ushort* __restrict__ APL,
    ushort* __restrict__ WPH, ushort* __restrict__ WPL)
{
    __shared__ float S[128][68];
    int t = threadIdx.x;

    if (blockIdx.x < CROP_BLOCKS) {
        int pt = blockIdx.x;
        if (pt >= BP) {
            u16x8 z8 = (u16x8)0;
            #pragma unroll
            for (int i = 0; i < 2; ++i) {
                int tau = t + i * 256;
                int step = tau >> 2, q = tau & 3;
                *(u16x8*)(APH + ((size_t)step * M_PAD + pt) * 32 + q * 8) = z8;
                *(u16x8*)(APL + ((size_t)step * M_PAD + pt) * 32 + q * 8) = z8;
            }
            return;
        }
        int b = pt / P_;
        int z = (int)rintf(z_pred[pt] - 1.0f);
        z = min(max(z, 0), D_SL_ - 1);
        int x = (int)rintf(4.0f * xy_pred[pt * 2 + 0]);
        int y = (int)rintf(4.0f * xy_pred[pt * 2 + 1]);
        x = min(max(x, 0), W_ - 1);
        y = min(max(y, 0), H_ - 1);
        const float* img = images + (size_t)(b * D_SL_ + z) * (H_ * W_);

        #pragma unroll
        for (int i = 0; i < 16; ++i) {
            int idx = t + i * 256;
            int r = idx >> 6, c = idx & 63;
            int iy = y - 32 + r, ix = x - 32 + c;
            float v = 0.0f;
            if ((unsigned)iy < (unsigned)H_ && (unsigned)ix < (unsigned)W_)
                v = img[iy * W_ + ix];
            S[r][c] = v;
        }
        __syncthreads();

        #pragma unroll
        for (int i = 0; i < 2; ++i) {
            int tau = t + i * 256;
            int step = tau >> 2, q = tau & 3;
            int r = step >> 1, cb = (step & 1) * 32 + q * 8;
            u16x8 vh, vl;
            #pragma unroll
            for (int e = 0; e < 8; ++e) {
                ushort hi, lo;
                split_bf16(S[r][cb + e], hi, lo);
                vh[e] = hi; vl[e] = lo;
            }
            *(u16x8*)(APH + ((size_t)step * M_PAD + pt) * 32 + q * 8) = vh;
            *(u16x8*)(APL + ((size_t)step * M_PAD + pt) * 32 + q * 8) = vl;
        }
        return;
    }

    int wb = blockIdx.x - CROP_BLOCKS;   // 0..639
    int k0 = (wb & 31) * 128;
    int n0 = (wb >> 5) * 64;
    #pragma unroll
    for (int p = 0; p < 8; ++p) {
        int kl = p * 16 + (t >> 4);
        int nq = (t & 15) * 4;
        const float* base = Wf + (size_t)(k0 + kl) * FOUT + n0 + nq;
        float4 a = *(const float4*)base;
        float4 b = *(const float4*)(base + (size_t)KPIX * FOUT);
        float4 c = *(const float4*)(base + (size_t)2 * KPIX * FOUT);
        *(float4*)&S[kl][nq] = make_float4(a.x + b.x + c.x, a.y + b.y + c.y,
                                           a.z + b.z + c.z, a.w + b.w + c.w);
    }
    __syncthreads();
    int stepl = t >> 6;
    int nl = t & 63;
    int gstep = (wb & 31) * 4 + stepl;
    ushort hi[32], lo[32];
    #pragma unroll
    for (int j = 0; j < 32; ++j) {
        float v = S[stepl * 32 + j][nl];
        split_bf16(v, hi[j], lo[j]);
    }
    ushort* oh = WPH + ((size_t)gstep * FOUT + n0 + nl) * 32;
    ushort* ol = WPL + ((size_t)gstep * FOUT + n0 + nl) * 32;
    #pragma unroll
    for (int q = 0; q < 4; ++q) {
        u16x8 vh, vl;
        #pragma unroll
        for (int e = 0; e < 8; ++e) { vh[e] = hi[q * 8 + e]; vl[e] = lo[q * 8 + e]; }
        *(u16x8*)(oh + q * 8) = vh;
        *(u16x8*)(ol + q * 8) = vl;
    }
}

// ---------------- MFMA GEMM (r3 core; 1D grid with kz->XCD swizzle) ----------------
// blockIdx.x = kz + 8*(m*10 + n): dispatch round-robins id%8 across XCDs, so all
// blocks of one k-chunk co-reside on one XCD -> panel slices stay in its 4MB L2.
__global__ __launch_bounds__(256) void gemm_mfma(
    const ushort* __restrict__ APH, const ushort* __restrict__ APL,
    const ushort* __restrict__ WPH, const ushort* __restrict__ WPL,
    float* __restrict__ part, float* __restrict__ out0)
{
    __shared__ ushort Atile[128 * 64];
    __shared__ ushort Btile[128 * 64];

    int t = threadIdx.x;
    int id = blockIdx.x;
    int kz = id & 7;
    int rr_ = id >> 3;               // 0..39
    int n0 = (rr_ % 10) * 128;
    int m0 = (rr_ / 10) * 128;
    int stepbase = kz * CH_STEPS;

    if (id == 0 && t == 0) out0[0] = 0.0f;

    int w = t >> 6, l = t & 63;
    int wm = w & 1, wn = w >> 1;
    int l16 = l & 15, kg = l >> 4;

    f32x4 acc[4][4];
    #pragma unroll
    for (int i = 0; i < 4; ++i)
        #pragma unroll
        for (int j = 0; j < 4; ++j) acc[i][j] = (f32x4){0.f, 0.f, 0.f, 0.f};

    int tr = t >> 1;
    int hb = (t & 1) * 8;
    int rm = tr & 15;

    u32x4 preA[4], preB[4];

#define LOADS(s_)                                                                   \
    {                                                                               \
        const ushort* asrc = ((t & 1) ? APL : APH)                                  \
            + ((size_t)(stepbase + (s_)) * M_PAD + m0 + tr) * 32;                   \
        const ushort* bsrc = ((t & 1) ? WPL : WPH)                                  \
            + ((size_t)(stepbase + (s_)) * FOUT + n0 + tr) * 32;                    \
        preA[0] = ((const u32x4*)asrc)[0]; preA[1] = ((const u32x4*)asrc)[1];       \
        preA[2] = ((const u32x4*)asrc)[2]; preA[3] = ((const u32x4*)asrc)[3];       \
        preB[0] = ((const u32x4*)bsrc)[0]; preB[1] = ((const u32x4*)bsrc)[1];       \
        preB[2] = ((const u32x4*)bsrc)[2]; preB[3] = ((const u32x4*)bsrc)[3];       \
    }

    LOADS(0);
    for (int s = 0; s < CH_STEPS; ++s) {
        __syncthreads();
        {
            ushort* arow = &Atile[tr * 64];
            ushort* brow = &Btile[tr * 64];
            #pragma unroll
            for (int q = 0; q < 4; ++q) {
                #pragma unroll
                for (int h = 0; h < 2; ++h) {
                    int j = q * 2 + h;
                    int u = (hb + j) ^ rm;
                    *(ull*)&arow[u * 4] = ((const ull*)&preA[q])[h];
                    *(ull*)&brow[u * 4] = ((const ull*)&preB[q])[h];
                }
            }
        }
        __syncthreads();
        if (s + 1 < CH_STEPS) LOADS(s + 1);

        union FragU { ull q[2]; bf16x8 v; };
        bf16x8 ah[4], al[4], bh[4], bl[4];
        #pragma unroll
        for (int mi = 0; mi < 4; ++mi) {
            int r = wm * 64 + mi * 16 + l16;
            const ushort* rowp = &Atile[r * 64];
            FragU fh, fl;
            fh.q[0] = *(const ull*)&rowp[(((2 * kg) ^ l16)) * 4];
            fh.q[1] = *(const ull*)&rowp[(((2 * kg + 1) ^ l16)) * 4];
            fl.q[0] = *(const ull*)&rowp[(((8 + 2 * kg) ^ l16)) * 4];
            fl.q[1] = *(const ull*)&rowp[(((9 + 2 * kg) ^ l16)) * 4];
            ah[mi] = fh.v; al[mi] = fl.v;
        }
        #pragma unroll
        for (int ni = 0; ni < 4; ++ni) {
            int r = wn * 64 + ni * 16 + l16;
            const ushort* rowp = &Btile[r * 64];
            FragU fh, fl;
            fh.q[0] = *(const ull*)&rowp[(((2 * kg) ^ l16)) * 4];
            fh.q[1] = *(const ull*)&rowp[(((2 * kg + 1) ^ l16)) * 4];
            fl.q[0] = *(const ull*)&rowp[(((8 + 2 * kg) ^ l16)) * 4];
            fl.q[1] = *(const ull*)&rowp[(((9 + 2 * kg) ^ l16)) * 4];
            bh[ni] = fh.v; bl[ni] = fl.v;
        }
        #pragma unroll
        for (int mi = 0; mi < 4; ++mi)
            #pragma unroll
            for (int ni = 0; ni < 4; ++ni) {
                acc[mi][ni] = __builtin_amdgcn_mfma_f32_16x16x32_bf16(ah[mi], bh[ni], acc[mi][ni], 0, 0, 0);
                acc[mi][ni] = __builtin_amdgcn_mfma_f32_16x16x32_bf16(ah[mi], bl[ni], acc[mi][ni], 0, 0, 0);
                acc[mi][ni] = __builtin_amdgcn_mfma_f32_16x16x32_bf16(al[mi], bh[ni], acc[mi][ni], 0, 0, 0);
            }
    }
#undef LOADS

    #pragma unroll
    for (int mi = 0; mi < 4; ++mi)
        #pragma unroll
        for (int ni = 0; ni < 4; ++ni)
            #pragma unroll
            for (int r = 0; r < 4; ++r) {
                int m = m0 + wm * 64 + mi * 16 + kg * 4 + r;
                if (m < BP) {
                    int n = n0 + wn * 64 + ni * 16 + l16;
                    part[((size_t)kz * BP + m) * FOUT + n] = acc[mi][ni][r];
                }
            }
}

// ---------------- MLP + softmax + fused loss: 4 rows/block, 4-way K-split ----------
__global__ __launch_bounds__(512) void mlp4_loss(
    const float* __restrict__ part,
    const float* __restrict__ bfeat,
    const float* __restrict__ W1, const float* __restrict__ b1,
    const float* __restrict__ W2, const float* __restrict__ b2,
    const int* __restrict__ grade,
    float* __restrict__ probs, float* __restrict__ out0)
{
    __shared__ float sf[4][FOUT];       // 20 KB
    __shared__ float shp[4][4][HID];    // [kquarter][row][j] 8 KB
    __shared__ float sh[4][HID];
    __shared__ float sl[4][NG];
    __shared__ float sden[512];
    int r0 = blockIdx.x * 4;            // 100 blocks
    int t = threadIdx.x;

    float dwt = 0.0f;
    if (t < BP) {
        int g = grade[t];
        dwt = (g == 0) ? 1.0f : (g == 1 ? 2.0f : 4.0f);
    }
    sden[t] = dwt;

    for (int i = t; i < 4 * FOUT; i += 512) {
        int r = i / FOUT, c = i - r * FOUT;
        size_t base = (size_t)(r0 + r) * FOUT + c;
        float v = bfeat[c];
        #pragma unroll
        for (int kzi = 0; kzi < KSPL; ++kzi)
            v += part[(size_t)kzi * BP * FOUT + base];
        sf[r][c] = v;
    }
    __syncthreads();
    for (int s = 256; s > 0; s >>= 1) {
        if (t < s) sden[t] += sden[t + s];
        __syncthreads();
    }
    float den = sden[0];

    {
        int kh = t >> 7, j = t & 127;   // kh: quarter of K (320 each)
        float a0 = (kh == 0) ? b1[j] : 0.0f, a1 = 0.0f, a2 = 0.0f, a3 = 0.0f;
        const float* wp = W1 + (size_t)(kh * 320) * HID + j;
        const float* s0 = &sf[0][kh * 320];
        const float* s1 = &sf[1][kh * 320];
        const float* s2 = &sf[2][kh * 320];
        const float* s3 = &sf[3][kh * 320];
        #pragma unroll 8
        for (int k = 0; k < 320; ++k) {
            float wv = wp[(size_t)k * HID];
            a0 = fmaf(s0[k], wv, a0);
            a1 = fmaf(s1[k], wv, a1);
            a2 = fmaf(s2[k], wv, a2);
            a3 = fmaf(s3[k], wv, a3);
        }
        shp[kh][0][j] = a0;
        shp[kh][1][j] = a1;
        shp[kh][2][j] = a2;
        shp[kh][3][j] = a3;
    }
    __syncthreads();
    {
        int rr = t >> 7, j = t & 127;
        sh[rr][j] = fmaxf(shp[0][rr][j] + shp[1][rr][j] + shp[2][rr][j] + shp[3][rr][j], 0.0f);
    }
    __syncthreads();
    if (t < 12) {
        int rr = t / 3, c = t - rr * 3;
        float a = b2[c];
        #pragma unroll 16
        for (int k = 0; k < HID; ++k) a = fmaf(sh[rr][k], W2[k * NG + c], a);
        sl[rr][c] = a;
    }
    __syncthreads();
    if (t < 4) {
        float l0 = sl[t][0], l1 = sl[t][1], l2 = sl[t][2];
        float m = fmaxf(l0, fmaxf(l1, l2));
        float e0 = expf(l0 - m), e1 = expf(l1 - m), e2 = expf(l2 - m);
        float inv = 1.0f / (e0 + e1 + e2);
        int row = r0 + t;
        probs[row * NG + 0] = e0 * inv;
        probs[row * NG + 1] = e1 * inv;
        probs[row * NG + 2] = e2 * inv;

        int g = grade[row];
        float lv = (g == 0) ? l0 : (g == 1 ? l1 : l2);
        lv = fminf(fmaxf(lv, 1e-5f), 1.0f - 1e-5f);
        float wt = (g == 0) ? 1.0f : (g == 1 ? 2.0f : 4.0f);
        atomicAdd(out0, -(wt * logf(lv)) / den);
    }
}

// ---------------- launch ----------------
extern "C" void kernel_launch(void* const* d_in, const int* in_sizes, int n_in,
                              void* d_out, int out_size, void* d_ws, size_t ws_size,
                              hipStream_t stream) {
    const float* images  = (const float*)d_in[0];
    const float* z_pred  = (const float*)d_in[1];
    const float* xy_pred = (const float*)d_in[2];
    const int*   grade   = (const int*)d_in[3];
    const float* W_feat  = (const float*)d_in[4];
    const float* b_feat  = (const float*)d_in[5];
    const float* W1      = (const float*)d_in[6];
    const float* b1      = (const float*)d_in[7];
    const float* W2      = (const float*)d_in[8];
    const float* b2      = (const float*)d_in[9];

    float* out = (float*)d_out;
    char* w = (char*)d_ws;
    ushort* APH = (ushort*)(w + OFF_APH);
    ushort* APL = (ushort*)(w + OFF_APL);
    ushort* WPH = (ushort*)(w + OFF_WPH);
    ushort* WPL = (ushort*)(w + OFF_WPL);
    float*  part = (float*)(w + OFF_PART);

    fused_prep<<<CROP_BLOCKS + 640, 256, 0, stream>>>(images, z_pred, xy_pred, W_feat,
                                                      APH, APL, WPH, WPL);
    gemm_mfma<<<10 * 4 * KSPL, 256, 0, stream>>>(APH, APL, WPH, WPL, part, out);
    mlp4_loss<<<BP / 4, 512, 0, stream>>>(part, b_feat, W1, b1, W2, b2, grade, out + 1, out);
}